// Round 4
// baseline (144.215 us; speedup 1.0000x reference)
//
#include <hip/hip_runtime.h>

// One block per row, N = 4096 hardcoded. Register-resident variant:
// thread t loads f32x2 at vec index j = t + 256k (k=0..7)  [8 B/lane, coalesced]
// holds all 16 floats in regs across the count-reduce, then emits output
// f32x4 at index j (each input pair -> one (1-a,a,1-b,b) quad) -> dense,
// wave-contiguous 1 KiB nontemporal store bursts. No LDS data staging at all;
// LDS is only 32 B of cross-wave reduce scratch.

typedef float f32x4 __attribute__((ext_vector_type(4)));
typedef float f32x2 __attribute__((ext_vector_type(2)));

constexpr int kN   = 4096;
constexpr int kNV2 = kN / 2;   // 2048 input f32x2 per row == output f32x4 per row
constexpr int kIter = kNV2 / 256;  // 8

__global__ __launch_bounds__(256) void StatsMode_kernel(
    const float* __restrict__ X, float* __restrict__ out) {
  __shared__ int red0[4], red1[4];

  const int row = blockIdx.x;
  const int tid = threadIdx.x;
  const f32x2* xrow = reinterpret_cast<const f32x2*>(X) + (size_t)row * kNV2;

  f32x2 v[kIter];
  #pragma unroll
  for (int k = 0; k < kIter; ++k)
    v[k] = __builtin_nontemporal_load(&xrow[tid + 256 * k]);

  int c0 = 0, c1 = 0;
  #pragma unroll
  for (int k = 0; k < kIter; ++k) {
    c0 += (v[k].x == 0.0f) + (v[k].y == 0.0f);
    c1 += (v[k].x == 1.0f) + (v[k].y == 1.0f);
  }

  // wave-level reduce (64 lanes)
  #pragma unroll
  for (int off = 32; off > 0; off >>= 1) {
    c0 += __shfl_down(c0, off, 64);
    c1 += __shfl_down(c1, off, 64);
  }
  const int wave = tid >> 6;
  if ((tid & 63) == 0) { red0[wave] = c0; red1[wave] = c1; }
  __syncthreads();

  const int t0 = red0[0] + red0[1] + red0[2] + red0[3];
  const int t1 = red1[0] + red1[1] + red1[2] + red1[3];
  // tie -> 0; all-invalid row (every entry -1) -> mode=1 reproduces the
  // reference's all-ones output through the fill path.
  const float mode = ((t0 + t1) == 0) ? 1.0f : ((t1 > t0) ? 1.0f : 0.0f);

  f32x4* orow = reinterpret_cast<f32x4*>(out) + (size_t)row * kNV2;
  #pragma unroll
  for (int k = 0; k < kIter; ++k) {
    const float a = (v[k].x == -1.0f) ? mode : v[k].x;
    const float b = (v[k].y == -1.0f) ? mode : v[k].y;
    f32x4 o; o.x = 1.0f - a; o.y = a; o.z = 1.0f - b; o.w = b;
    __builtin_nontemporal_store(o, &orow[tid + 256 * k]);
  }
}

extern "C" void kernel_launch(void* const* d_in, const int* in_sizes, int n_in,
                              void* d_out, int out_size, void* d_ws, size_t ws_size,
                              hipStream_t stream) {
  const float* X = (const float*)d_in[0];
  float* out = (float*)d_out;
  const int B = in_sizes[0] / kN;   // 16384
  StatsMode_kernel<<<B, 256, 0, stream>>>(X, out);
}